// Round 15
// baseline (4913.974 us; speedup 1.0000x reference)
//
#include <hip/hip_runtime.h>

typedef unsigned int u32;
typedef unsigned short u16;
typedef short bf16x8 __attribute__((ext_vector_type(8)));
typedef float f32x4 __attribute__((ext_vector_type(4)));

#define TLEN 1000
#define BATCH 128
#define IDIM 64
#define HDIM 512

#define NWG 128
#define NTHR 256

// ws byte offsets: h0/h1 are 4-deep (slot = tick & 3)
#define H0_OFF 0
#define H1_OFF 524288
#define PX0_OFF 1048576
#define PH0_OFF 1245184
#define PX1_OFF 2818048
#define PH1_OFF 4390912
#define FLG_OFF 5963776
#define XSL_OFF 5967872

__device__ __forceinline__ u16 f2bf(float f) {
  u32 u = __float_as_uint(f);
  u += 0x7fffu + ((u >> 16) & 1u);
  return (u16)(u >> 16);
}
__device__ __forceinline__ float bf2f(u16 h) { return __uint_as_float(((u32)h) << 16); }
__device__ __forceinline__ float sigm(float x) { return 1.0f / (1.0f + __expf(-x)); }
__device__ __forceinline__ float tanhfast(float x) {
  float e = __expf(-2.0f * fabsf(x));
  float t = (1.0f - e) / (1.0f + e);
  return x >= 0.0f ? t : -t;
}
__device__ __forceinline__ u32 umin2(u32 a, u32 b) { return a < b ? a : b; }
__device__ __forceinline__ u32 umax2(u32 a, u32 b) { return a > b ? a : b; }

// ---- system scope (sc0 sc1): proven r6-r14 ----
__device__ __forceinline__ void sys_st16(u16* p, u32 v) {
  asm volatile("global_store_short %0, %1, off sc0 sc1" ::"v"(p), "v"(v) : "memory");
}
__device__ __forceinline__ void sys_st32(u32* p, u32 v) {
  asm volatile("global_store_dword %0, %1, off sc0 sc1" ::"v"(p), "v"(v) : "memory");
}
__device__ __forceinline__ uint4 sys_ld128(const u32* p) {
  uint4 v;
  asm volatile("global_load_dwordx4 %0, %1, off sc0 sc1\n\ts_waitcnt vmcnt(0)"
               : "=v"(v) : "v"(p) : "memory");
  return v;
}
__device__ __forceinline__ void sys_ldA(bf16x8& d, const u16* p) {
  asm volatile("global_load_dwordx4 %0, %1, off sc0 sc1" : "=v"(d) : "v"(p));
}
// ---- sc0 ops: XCD-L2 coherent for DATA (r11/r13); flags only as FAST copy ----
__device__ __forceinline__ void l2_st16(u16* p, u32 v) {
  asm volatile("global_store_short %0, %1, off sc0" ::"v"(p), "v"(v) : "memory");
}
__device__ __forceinline__ void l2_st32(u32* p, u32 v) {
  asm volatile("global_store_dword %0, %1, off sc0" ::"v"(p), "v"(v) : "memory");
}
__device__ __forceinline__ uint4 l2_ld128(const u32* p) {
  uint4 v;
  asm volatile("global_load_dwordx4 %0, %1, off sc0\n\ts_waitcnt vmcnt(0)"
               : "=v"(v) : "v"(p) : "memory");
  return v;
}
__device__ __forceinline__ void l2_ldA(bf16x8& d, const u16* p) {
  asm volatile("global_load_dwordx4 %0, %1, off sc0" : "=v"(d) : "v"(p));
}

// ---------------- weight pre-pack into MFMA B-fragment order (unchanged) ------
__global__ void pack_weights(const float* Wih0, const float* Whh0,
                             const float* Wih1, const float* Whh1, char* ws) {
  int fid = blockIdx.x * NTHR + threadIdx.x;
  const float* src;
  int K, Kks;
  size_t obase;
  int f = fid;
  if (f < 12288) {
    src = Wih0; K = 64; Kks = 2; obase = PX0_OFF;
  } else if (f < 12288 + 98304) {
    f -= 12288; src = Whh0; K = 512; Kks = 16; obase = PH0_OFF;
  } else if (f < 12288 + 2 * 98304) {
    f -= 12288 + 98304; src = Wih1; K = 512; Kks = 16; obase = PX1_OFF;
  } else if (f < 12288 + 3 * 98304) {
    f -= 12288 + 2 * 98304; src = Whh1; K = 512; Kks = 16; obase = PH1_OFF;
  } else {
    return;
  }
  int lane = f & 63;
  int r = f >> 6;
  int ks = r % Kks; r /= Kks;
  int ct = r % 3;
  int sl = r / 3;
  int grow = ct * 512 + sl * 16 + (lane & 15);
  int k = ks * 32 + ((lane >> 4) * 8);
  const float* s = src + (size_t)grow * K + k;
  u32 p0 = f2bf(s[0]) | ((u32)f2bf(s[1]) << 16);
  u32 p1 = f2bf(s[2]) | ((u32)f2bf(s[3]) << 16);
  u32 p2 = f2bf(s[4]) | ((u32)f2bf(s[5]) << 16);
  u32 p3 = f2bf(s[6]) | ((u32)f2bf(s[7]) << 16);
  *(uint4*)(ws + obase + (size_t)f * 16) = make_uint4(p0, p1, p2, p3);
}

struct KP {
  const float *x, *bih0, *bhh0, *bih1, *bhh1, *Wfc, *bfc;
  float* out;
  char* ws;
};

#define MFMA(A, B, C) __builtin_amdgcn_mfma_f32_16x16x32_bf16((A), (B), (C), 0, 0, 0)

// wait: min over 16 flags (max of sys/fast views) >= k
__device__ __forceinline__ void wait_flags(const u32* fls, const u32* flf, u32 k) {
  if (threadIdx.x < 64) {
    const int lane = threadIdx.x;
    for (;;) {
      u32 m = 0xFFFFFFFFu;
      if (lane < 4) {
        uint4 v = sys_ld128(fls + lane * 4);
        m = umin2(umin2(v.x, v.y), umin2(v.z, v.w));
      } else if (lane < 8) {
        uint4 v = l2_ld128(flf + (lane - 4) * 4);
        m = umin2(umin2(v.x, v.y), umin2(v.z, v.w));
      }
      m = umax2(m, __shfl_xor(m, 4));  // best of sys/fast per quad
      m = umin2(m, __shfl_xor(m, 1));
      m = umin2(m, __shfl_xor(m, 2));
      if (__shfl(m, 0) >= k) break;
      __builtin_amdgcn_s_sleep(1);
    }
  }
  __syncthreads();
}

__global__ __launch_bounds__(NTHR, 1) void gru_main(KP P) {
  __shared__ f32x4 red[4][8][64];  // 32 KB cross-wave reduce (reused L0 then L1)
  const int tid = threadIdx.x;
  const int lane = tid & 63;
  const int w = tid >> 6;        // K-quarter (ksteps == w mod 4)
  const int b = blockIdx.x;
  const int bg = b & 7;          // cluster: 8 batch groups x 16 rows; b%8 -> XCD round-robin
  const int colWG = b >> 3;      // 16 col groups x 32 cols (both layers)

  char* ws = P.ws;
  u16* h0 = (u16*)(ws + H0_OFF);
  u16* h1 = (u16*)(ws + H1_OFF);
  u32* fb = (u32*)(ws + FLG_OFF) + bg * 128;
  u32* fls = fb;           // sys copy (16 u32, one 64B line)
  u32* flf = fb + 32;      // fast (sc0) copy
  u32* xsl = (u32*)(ws + XSL_OFF) + bg * 64;  // 0..15 xcc, 32..47 phase-A flags
  u32* phf = xsl + 32;
  const bf16x8* px0 = (const bf16x8*)(ws + PX0_OFF);
  const bf16x8* ph0 = (const bf16x8*)(ws + PH0_OFF);
  const bf16x8* px1 = (const bf16x8*)(ws + PX1_OFF);
  const bf16x8* ph1 = (const bf16x8*)(ws + PH1_OFF);

  const int cw = w & 1;  // col-slice owned in gate phase (waves 0,1)
  const int jcol = colWG * 32 + cw * 16 + (lane & 15);
  const float b_r0 = P.bih0[jcol] + P.bhh0[jcol];
  const float b_z0 = P.bih0[HDIM + jcol] + P.bhh0[HDIM + jcol];
  const float b_nx0 = P.bih0[2 * HDIM + jcol];
  const float b_nh0 = P.bhh0[2 * HDIM + jcol];
  const float b_r1 = P.bih1[jcol] + P.bhh1[jcol];
  const float b_z1 = P.bih1[HDIM + jcol] + P.bhh1[HDIM + jcol];
  const float b_nx1 = P.bih1[2 * HDIM + jcol];
  const float b_nh1 = P.bhh1[2 * HDIM + jcol];

  const size_t bgoff = (size_t)bg * 16 * HDIM;
  const size_t SLOT = (size_t)BATCH * HDIM;

  // ---- persistent B fragments, both layers: sl = colWG*2 + cs; kstep = j*4+w ----
  bf16x8 xB0[3][2];                    // L0 x-gemm K=64: wave w<2 owns kstep w
  bf16x8 hB0[3][2][4], xB1[3][2][4], hB1[3][2][4];
#pragma unroll
  for (int ct = 0; ct < 3; ++ct)
#pragma unroll
    for (int cs = 0; cs < 2; ++cs) {
      const int sl = colWG * 2 + cs;
#pragma unroll
      for (int j = 0; j < 4; ++j) {
        hB0[ct][cs][j] = ph0[((size_t)(sl * 3 + ct) * 16 + (j * 4 + w)) * 64 + lane];
        xB1[ct][cs][j] = px1[((size_t)(sl * 3 + ct) * 16 + (j * 4 + w)) * 64 + lane];
        hB1[ct][cs][j] = ph1[((size_t)(sl * 3 + ct) * 16 + (j * 4 + w)) * 64 + lane];
      }
      if (w < 2) xB0[ct][cs] = px0[((size_t)(sl * 3 + ct) * 2 + w) * 64 + lane];
      else { const bf16x8 z8 = {0,0,0,0,0,0,0,0}; xB0[ct][cs] = z8; }
    }

  // ---- phase A: publish XCC_ID, one sys cluster barrier, locality verdict ----
  u32 xcc = 0;
  asm volatile("s_getreg_b32 %0, hwreg(HW_REG_XCC_ID)" : "=s"(xcc));
  if (tid == 0) sys_st32(xsl + colWG, xcc + 1u);
  __syncthreads();
  if (tid == 0) sys_st32(phf + colWG, 1u);
  if (tid < 64) {
    for (;;) {
      u32 m = 0xFFFFFFFFu;
      if (lane < 4) {
        uint4 v = sys_ld128(phf + lane * 4);
        m = umin2(umin2(v.x, v.y), umin2(v.z, v.w));
      }
      m = umin2(m, __shfl_xor(m, 1));
      m = umin2(m, __shfl_xor(m, 2));
      if (__shfl(m, 0) >= 1u) break;
      __builtin_amdgcn_s_sleep(2);
    }
  }
  __syncthreads();
  u32 mn = 0xFFFFFFFFu, mx = 0u;
  if (lane < 4) {
    uint4 v = sys_ld128(xsl + lane * 4);
    mn = umin2(umin2(v.x, v.y), umin2(v.z, v.w));
    mx = umax2(umax2(v.x, v.y), umax2(v.z, v.w));
  }
  mn = umin2(mn, __shfl_xor(mn, 1)); mx = umax2(mx, __shfl_xor(mx, 1));
  mn = umin2(mn, __shfl_xor(mn, 2)); mx = umax2(mx, __shfl_xor(mx, 2));
  mn = __shfl(mn, 0); mx = __shfl(mx, 0);
  const bool isLocal = (mn != 0u) && (mn == mx);

  const f32x4 zf = {0.f, 0.f, 0.f, 0.f};
  f32x4 hown0 = zf, hown1 = zf;

#pragma unroll 1
  for (int k = 0; k <= TLEN; ++k) {
    const bool doL0 = (k < TLEN);
    const bool doL1 = (k >= 1);
    f32x4 aR[2], aZ[2], aXN[2], aHN[2];
#pragma unroll
    for (int cs = 0; cs < 2; ++cs) { aR[cs] = zf; aZ[cs] = zf; aXN[cs] = zf; aHN[cs] = zf; }

    // ---- L0 x-gemm for tick k BEFORE the wait (barrier-independent) ----
    if (doL0 && w < 2) {
      const float* s = P.x + ((size_t)(bg * 16 + (lane & 15)) * TLEN + k) * IDIM +
                       w * 32 + ((lane >> 4) * 8);
      float4 v0 = ((const float4*)s)[0];
      float4 v1 = ((const float4*)s)[1];
      bf16x8 A;
      A[0] = (short)f2bf(v0.x); A[1] = (short)f2bf(v0.y);
      A[2] = (short)f2bf(v0.z); A[3] = (short)f2bf(v0.w);
      A[4] = (short)f2bf(v1.x); A[5] = (short)f2bf(v1.y);
      A[6] = (short)f2bf(v1.z); A[7] = (short)f2bf(v1.w);
#pragma unroll
      for (int cs = 0; cs < 2; ++cs) {
        aR[cs] = MFMA(A, xB0[0][cs], aR[cs]);
        aZ[cs] = MFMA(A, xB0[1][cs], aZ[cs]);
        aXN[cs] = MFMA(A, xB0[2][cs], aXN[cs]);
      }
    }

    if (k > 0) wait_flags(fls, flf, (u32)k);

    // ---- issue ALL h loads: h0[k-1] (shared by L0-h and L1-x) + h1[k-2] ----
    const u16* h0src = h0 + (size_t)((k + 3) & 3) * SLOT + bgoff;
    const u16* h1src = h1 + (size_t)((k + 2) & 3) * SLOT + bgoff;
    bf16x8 A0[4], A1[4];
    if (isLocal) {
#pragma unroll
      for (int j = 0; j < 4; ++j) {
        const size_t off = (size_t)(lane & 15) * HDIM + (j * 4 + w) * 32 + ((lane >> 4) * 8);
        l2_ldA(A0[j], h0src + off);
        if (doL1) l2_ldA(A1[j], h1src + off);
      }
    } else {
#pragma unroll
      for (int j = 0; j < 4; ++j) {
        const size_t off = (size_t)(lane & 15) * HDIM + (j * 4 + w) * 32 + ((lane >> 4) * 8);
        sys_ldA(A0[j], h0src + off);
        if (doL1) sys_ldA(A1[j], h1src + off);
      }
    }
    asm volatile("s_waitcnt vmcnt(0)" ::: "memory");
    __builtin_amdgcn_sched_barrier(0);

    if (doL0) {
      // ---- L0 h-gemm ----
#pragma unroll
      for (int j = 0; j < 4; ++j)
#pragma unroll
        for (int cs = 0; cs < 2; ++cs) {
          aR[cs] = MFMA(A0[j], hB0[0][cs][j], aR[cs]);
          aZ[cs] = MFMA(A0[j], hB0[1][cs][j], aZ[cs]);
          aHN[cs] = MFMA(A0[j], hB0[2][cs][j], aHN[cs]);
        }
      // ---- L0 reduce + gates + store h0[k] ----
#pragma unroll
      for (int cs = 0; cs < 2; ++cs) {
        red[w][0 + cs][lane] = aR[cs];
        red[w][2 + cs][lane] = aZ[cs];
        red[w][4 + cs][lane] = aXN[cs];
        red[w][6 + cs][lane] = aHN[cs];
      }
      __syncthreads();
      f32x4 R = zf, Z = zf, XN = zf, HN = zf;
#pragma unroll
      for (int kq = 0; kq < 4; ++kq) {
        R = R + red[kq][0 + cw][lane];
        Z = Z + red[kq][2 + cw][lane];
        XN = XN + red[kq][4 + cw][lane];
        HN = HN + red[kq][6 + cw][lane];
      }
      __syncthreads();  // red free for L1
      if (w < 2) {
        u16* hw = h0 + (size_t)(k & 3) * SLOT;
#pragma unroll
        for (int qq = 0; qq < 4; ++qq) {
          float r = sigm(R[qq] + b_r0);
          float z = sigm(Z[qq] + b_z0);
          float n = tanhfast(XN[qq] + b_nx0 + r * (HN[qq] + b_nh0));
          float hv = (1.f - z) * n + z * hown0[qq];
          hown0[qq] = hv;
          int rowb = bg * 16 + (lane >> 4) * 4 + qq;
          if (isLocal) l2_st16(&hw[(size_t)rowb * HDIM + jcol], (u32)f2bf(hv));
          else sys_st16(&hw[(size_t)rowb * HDIM + jcol], (u32)f2bf(hv));
        }
      }
    }

    if (doL1) {
      // ---- L1 gemms: x-input = h0[k-1] (A0, shared), recurrent = h1[k-2] (A1) ----
#pragma unroll
      for (int cs = 0; cs < 2; ++cs) { aR[cs] = zf; aZ[cs] = zf; aXN[cs] = zf; aHN[cs] = zf; }
#pragma unroll
      for (int j = 0; j < 4; ++j)
#pragma unroll
        for (int cs = 0; cs < 2; ++cs) {
          aR[cs] = MFMA(A0[j], xB1[0][cs][j], aR[cs]);
          aZ[cs] = MFMA(A0[j], xB1[1][cs][j], aZ[cs]);
          aXN[cs] = MFMA(A0[j], xB1[2][cs][j], aXN[cs]);
        }
#pragma unroll
      for (int j = 0; j < 4; ++j)
#pragma unroll
        for (int cs = 0; cs < 2; ++cs) {
          aR[cs] = MFMA(A1[j], hB1[0][cs][j], aR[cs]);
          aZ[cs] = MFMA(A1[j], hB1[1][cs][j], aZ[cs]);
          aHN[cs] = MFMA(A1[j], hB1[2][cs][j], aHN[cs]);
        }
      // ---- L1 reduce + gates + store h1[k-1] ----
#pragma unroll
      for (int cs = 0; cs < 2; ++cs) {
        red[w][0 + cs][lane] = aR[cs];
        red[w][2 + cs][lane] = aZ[cs];
        red[w][4 + cs][lane] = aXN[cs];
        red[w][6 + cs][lane] = aHN[cs];
      }
      __syncthreads();
      f32x4 R = zf, Z = zf, XN = zf, HN = zf;
#pragma unroll
      for (int kq = 0; kq < 4; ++kq) {
        R = R + red[kq][0 + cw][lane];
        Z = Z + red[kq][2 + cw][lane];
        XN = XN + red[kq][4 + cw][lane];
        HN = HN + red[kq][6 + cw][lane];
      }
      __syncthreads();  // red free for next iter
      if (w < 2) {
        u16* hw = h1 + (size_t)((k + 3) & 3) * SLOT;
#pragma unroll
        for (int qq = 0; qq < 4; ++qq) {
          float r = sigm(R[qq] + b_r1);
          float z = sigm(Z[qq] + b_z1);
          float n = tanhfast(XN[qq] + b_nx1 + r * (HN[qq] + b_nh1));
          float hv = (1.f - z) * n + z * hown1[qq];
          hown1[qq] = hv;
          int rowb = bg * 16 + (lane >> 4) * 4 + qq;
          if (isLocal) l2_st16(&hw[(size_t)rowb * HDIM + jcol], (u32)f2bf(hv));
          else sys_st16(&hw[(size_t)rowb * HDIM + jcol], (u32)f2bf(hv));
        }
      }
    }

    // ---- single signal: iteration k complete (flag = k+1), dual scope ----
    __syncthreads();  // all waves' h stores issued (compiler drains vmcnt)
    if (tid == 0) {
      asm volatile("s_waitcnt vmcnt(0)" ::: "memory");
      l2_st32(flf + colWG, (u32)(k + 1));
      sys_st32(fls + colWG, (u32)(k + 1));
    }
  }

  // ---- final FC + sigmoid: needs flags >= TLEN+1; h1[999] = slot 3 ----
  if (colWG == 0) {
    wait_flags(fls, flf, (u32)(TLEN + 1));
    const u16* hT = h1 + (size_t)((TLEN + 3) & 3) * SLOT;
    int row = tid >> 4, qq = tid & 15;
    const u16* hr = hT + (size_t)(bg * 16 + row) * HDIM + qq * 32;
    bf16x8 hv[4];
    if (isLocal) {
#pragma unroll
      for (int c = 0; c < 4; ++c) l2_ldA(hv[c], hr + c * 8);
    } else {
#pragma unroll
      for (int c = 0; c < 4; ++c) sys_ldA(hv[c], hr + c * 8);
    }
    asm volatile("s_waitcnt vmcnt(0)" ::: "memory");
    const float* wf = P.Wfc + qq * 32;
    float s = 0.f;
#pragma unroll
    for (int c = 0; c < 4; ++c)
#pragma unroll
      for (int k2 = 0; k2 < 8; ++k2) s += bf2f((u16)hv[c][k2]) * wf[c * 8 + k2];
    s += __shfl_xor(s, 1);
    s += __shfl_xor(s, 2);
    s += __shfl_xor(s, 4);
    s += __shfl_xor(s, 8);
    if (qq == 0) P.out[bg * 16 + row] = sigm(s + P.bfc[0]);
  }
}

extern "C" void kernel_launch(void* const* d_in, const int* in_sizes, int n_in,
                              void* d_out, int out_size, void* d_ws, size_t ws_size,
                              hipStream_t stream) {
  const float* x = (const float*)d_in[0];
  const float* Wih0 = (const float*)d_in[1];
  const float* Whh0 = (const float*)d_in[2];
  const float* bih0 = (const float*)d_in[3];
  const float* bhh0 = (const float*)d_in[4];
  const float* Wih1 = (const float*)d_in[5];
  const float* Whh1 = (const float*)d_in[6];
  const float* bih1 = (const float*)d_in[7];
  const float* bhh1 = (const float*)d_in[8];
  const float* Wfc = (const float*)d_in[9];
  const float* bfc = (const float*)d_in[10];

  hipMemsetAsync(d_ws, 0, 1048576, stream);                      // h0/h1 x 4 slots
  hipMemsetAsync((char*)d_ws + FLG_OFF, 0, 6144, stream);        // flags + xcc/phaseA
  pack_weights<<<dim3(1200), dim3(NTHR), 0, stream>>>(Wih0, Whh0, Wih1, Whh1, (char*)d_ws);

  KP P = {x, bih0, bhh0, bih1, bhh1, Wfc, bfc, (float*)d_out, (char*)d_ws};
  void* args[] = {&P};
  hipError_t ce = hipLaunchCooperativeKernel((void*)gru_main, dim3(NWG), dim3(NTHR), args, 0,
                                             stream);
  if (ce != hipSuccess) {
    // 128 WGs x 4 waves, 32KB LDS: fully co-resident on 256 CUs; sync is
    // hand-rolled monotonic flags, so a plain launch is safe.
    (void)hipGetLastError();  // clear error state
    gru_main<<<dim3(NWG), dim3(NTHR), 0, stream>>>(P);
  }
}